// Round 1
// baseline (2245.570 us; speedup 1.0000x reference)
//
#include <hip/hip_runtime.h>

// CNN self-attention: B=4, C=256 (in==out), H=W=64 -> N=4096.
// Round 0: fp32-everything correctness baseline.
//   Kernel 1: fused QKV 1x1-conv projection (x-tile reused for all 3 GEMMs).
//   Kernel 2: flash attention (Q-tile 32 rows/block, K/V streamed in 64x64 LDS
//             chunks, online softmax, LDS-transposed coalesced epilogue).
// Workspace: Q,K,V as [B][N][C] fp32 = 48 MB (requires ws_size >= 50331648).

#define NB 4
#define NC 256
#define NN 4096

// ---------------- Kernel 1: QKV projection ----------------
// Q[b][n][c] = sum_ci Wq[c][ci] * x[b][ci][n] + bq[c]   (same for K, V)
__global__ __launch_bounds__(256) void qkv_proj_kernel(
    const float* __restrict__ x,
    const float* __restrict__ Wq, const float* __restrict__ Wk, const float* __restrict__ Wv,
    const float* __restrict__ bq, const float* __restrict__ bk, const float* __restrict__ bv,
    float* __restrict__ Q, float* __restrict__ K, float* __restrict__ V)
{
    const int b  = blockIdx.z;
    const int n0 = blockIdx.x * 64;
    const int c0 = blockIdx.y * 64;
    const int t  = threadIdx.x;

    __shared__ float xs[16][68];   // [ci][n]
    __shared__ float wqs[16][68];  // [ci][c] (transposed on load)
    __shared__ float wks[16][68];
    __shared__ float wvs[16][68];

    const int tn = (t & 15) * 4;   // n micro-offset
    const int tc = (t >> 4) * 4;   // c micro-offset

    float aq[4][4] = {}, ak[4][4] = {}, av[4][4] = {};

    const float* xb = x + (size_t)b * NC * NN;

    for (int k0 = 0; k0 < NC; k0 += 16) {
        __syncthreads();
        {   // x chunk [16 ci][64 n], coalesced float4
            const int ci = t >> 4;
            const int nb = (t & 15) * 4;
            *(float4*)&xs[ci][nb] =
                *(const float4*)(xb + (size_t)(k0 + ci) * NN + n0 + nb);
        }
        {   // W chunks [64 c][16 ci] -> LDS transposed [ci][c]
            const int c  = t >> 2;
            const int cb = (t & 3) * 4;
            const float4 q4 = *(const float4*)(Wq + (size_t)(c0 + c) * NC + k0 + cb);
            const float4 k4 = *(const float4*)(Wk + (size_t)(c0 + c) * NC + k0 + cb);
            const float4 v4 = *(const float4*)(Wv + (size_t)(c0 + c) * NC + k0 + cb);
            wqs[cb + 0][c] = q4.x; wqs[cb + 1][c] = q4.y; wqs[cb + 2][c] = q4.z; wqs[cb + 3][c] = q4.w;
            wks[cb + 0][c] = k4.x; wks[cb + 1][c] = k4.y; wks[cb + 2][c] = k4.z; wks[cb + 3][c] = k4.w;
            wvs[cb + 0][c] = v4.x; wvs[cb + 1][c] = v4.y; wvs[cb + 2][c] = v4.z; wvs[cb + 3][c] = v4.w;
        }
        __syncthreads();
        #pragma unroll
        for (int kk = 0; kk < 16; ++kk) {
            float a[4], wq_[4], wk_[4], wv_[4];
            *(float4*)a   = *(const float4*)&xs[kk][tn];
            *(float4*)wq_ = *(const float4*)&wqs[kk][tc];
            *(float4*)wk_ = *(const float4*)&wks[kk][tc];
            *(float4*)wv_ = *(const float4*)&wvs[kk][tc];
            #pragma unroll
            for (int i = 0; i < 4; ++i) {
                #pragma unroll
                for (int j = 0; j < 4; ++j) {
                    aq[i][j] += a[i] * wq_[j];
                    ak[i][j] += a[i] * wk_[j];
                    av[i][j] += a[i] * wv_[j];
                }
            }
        }
    }

    float bqv[4], bkv[4], bvv[4];
    *(float4*)bqv = *(const float4*)(bq + c0 + tc);
    *(float4*)bkv = *(const float4*)(bk + c0 + tc);
    *(float4*)bvv = *(const float4*)(bv + c0 + tc);

    #pragma unroll
    for (int i = 0; i < 4; ++i) {
        const size_t base = ((size_t)b * NN + n0 + tn + i) * NC + c0 + tc;
        *(float4*)(Q + base) = make_float4(aq[i][0] + bqv[0], aq[i][1] + bqv[1],
                                           aq[i][2] + bqv[2], aq[i][3] + bqv[3]);
        *(float4*)(K + base) = make_float4(ak[i][0] + bkv[0], ak[i][1] + bkv[1],
                                           ak[i][2] + bkv[2], ak[i][3] + bkv[3]);
        *(float4*)(V + base) = make_float4(av[i][0] + bvv[0], av[i][1] + bvv[1],
                                           av[i][2] + bvv[2], av[i][3] + bvv[3]);
    }
}

// ---------------- Kernel 2: flash attention ----------------
// Per block: 32 q-rows. Iterate 64-wide k-tiles: S = Q.K^T (fp32), online
// softmax, O += P.V. Thread t: row-group rg=t/32 owns rows r0..r0+3 (each
// row-group == one 32-lane wave half -> shuffle reductions + wave-coherent Ps).
__global__ __launch_bounds__(256) void flash_attn_kernel(
    const float* __restrict__ Q, const float* __restrict__ K, const float* __restrict__ V,
    float* __restrict__ out)
{
    const int b  = blockIdx.y;
    const int n0 = blockIdx.x * 32;
    const int t  = threadIdx.x;

    __shared__ float Qs[32][260];  // 32 q-rows x 256 ch (pad->stride 260)
    __shared__ float KV[64][68];   // K chunk [m][c] / V chunk [m][ch] / O transpose
    __shared__ float Ps[32][68];   // P tile [q-row][k-col]

    // Load Q tile [32][256]
    #pragma unroll
    for (int r = 0; r < 8; ++r) {
        const int f   = t + r * 256;   // float4 index
        const int row = f >> 6;
        const int cb  = (f & 63) * 4;
        *(float4*)&Qs[row][cb] =
            *(const float4*)(Q + ((size_t)b * NN + n0 + row) * NC + cb);
    }

    const int r0 = (t >> 5) * 4;   // rows owned
    const int cl = t & 31;         // col lane within row-group

    float m_i[4] = {-1e30f, -1e30f, -1e30f, -1e30f};
    float l_i[4] = {};
    float O[4][4][2] = {};         // [ch-chunk][row][col]

    for (int kt = 0; kt < NN / 64; ++kt) {
        const int m0 = kt * 64;
        float s[4][2] = {};        // S[r0+i][cl], S[r0+i][cl+32]

        // ---- S = Q . K^T, contraction chunked by 64 channels ----
        #pragma unroll
        for (int cc = 0; cc < 4; ++cc) {
            __syncthreads();
            #pragma unroll
            for (int r = 0; r < 4; ++r) {
                const int f  = t + r * 256;
                const int m  = f >> 4;
                const int cb = (f & 15) * 4;
                *(float4*)&KV[m][cb] =
                    *(const float4*)(K + ((size_t)b * NN + m0 + m) * NC + cc * 64 + cb);
            }
            __syncthreads();
            #pragma unroll
            for (int c4 = 0; c4 < 64; c4 += 4) {
                float k0[4], k1[4];
                *(float4*)k0 = *(const float4*)&KV[cl][c4];
                *(float4*)k1 = *(const float4*)&KV[cl + 32][c4];
                #pragma unroll
                for (int i = 0; i < 4; ++i) {
                    float q4[4];
                    *(float4*)q4 = *(const float4*)&Qs[r0 + i][cc * 64 + c4];
                    s[i][0] += q4[0]*k0[0] + q4[1]*k0[1] + q4[2]*k0[2] + q4[3]*k0[3];
                    s[i][1] += q4[0]*k1[0] + q4[1]*k1[1] + q4[2]*k1[2] + q4[3]*k1[3];
                }
            }
        }

        // ---- online softmax (row reductions across the 32-lane group) ----
        float alpha[4];
        #pragma unroll
        for (int i = 0; i < 4; ++i) {
            float tm = fmaxf(s[i][0], s[i][1]);
            #pragma unroll
            for (int off = 16; off >= 1; off >>= 1)
                tm = fmaxf(tm, __shfl_xor(tm, off));
            const float mnew = fmaxf(m_i[i], tm);
            alpha[i] = __expf(m_i[i] - mnew);
            m_i[i]   = mnew;
            const float p0 = __expf(s[i][0] - mnew);
            const float p1 = __expf(s[i][1] - mnew);
            Ps[r0 + i][cl]      = p0;
            Ps[r0 + i][cl + 32] = p1;
            float ps = p0 + p1;
            #pragma unroll
            for (int off = 16; off >= 1; off >>= 1)
                ps += __shfl_xor(ps, off);
            l_i[i] = l_i[i] * alpha[i] + ps;
        }
        #pragma unroll
        for (int vc = 0; vc < 4; ++vc)
            #pragma unroll
            for (int i = 0; i < 4; ++i) {
                O[vc][i][0] *= alpha[i];
                O[vc][i][1] *= alpha[i];
            }

        // ---- O += P . V, channels chunked by 64 ----
        #pragma unroll
        for (int vc = 0; vc < 4; ++vc) {
            __syncthreads();
            #pragma unroll
            for (int r = 0; r < 4; ++r) {
                const int f  = t + r * 256;
                const int m  = f >> 4;
                const int cb = (f & 15) * 4;
                *(float4*)&KV[m][cb] =
                    *(const float4*)(V + ((size_t)b * NN + m0 + m) * NC + vc * 64 + cb);
            }
            __syncthreads();
            #pragma unroll
            for (int m4 = 0; m4 < 64; m4 += 4) {
                float p[4][4];
                #pragma unroll
                for (int i = 0; i < 4; ++i)
                    *(float4*)p[i] = *(const float4*)&Ps[r0 + i][m4];
                #pragma unroll
                for (int mm = 0; mm < 4; ++mm) {
                    float v2[2];
                    *(float2*)v2 = *(const float2*)&KV[m4 + mm][cl * 2];
                    #pragma unroll
                    for (int i = 0; i < 4; ++i) {
                        O[vc][i][0] += p[i][mm] * v2[0];
                        O[vc][i][1] += p[i][mm] * v2[1];
                    }
                }
            }
        }
    }

    // ---- normalize + coalesced store via LDS transpose ----
    float inv[4];
    #pragma unroll
    for (int i = 0; i < 4; ++i) inv[i] = 1.0f / l_i[i];

    #pragma unroll
    for (int vc = 0; vc < 4; ++vc) {
        __syncthreads();
        #pragma unroll
        for (int i = 0; i < 4; ++i) {
            KV[cl * 2 + 0][r0 + i] = O[vc][i][0] * inv[i];
            KV[cl * 2 + 1][r0 + i] = O[vc][i][1] * inv[i];
        }
        __syncthreads();
        const int n  = t & 31;
        const int cg = t >> 5;
        #pragma unroll
        for (int ccp = 0; ccp < 8; ++ccp) {
            const int ch = cg * 8 + ccp;
            out[((size_t)b * NC + vc * 64 + ch) * NN + n0 + n] = KV[ch][n];
        }
    }
}

extern "C" void kernel_launch(void* const* d_in, const int* in_sizes, int n_in,
                              void* d_out, int out_size, void* d_ws, size_t ws_size,
                              hipStream_t stream)
{
    const float* x  = (const float*)d_in[0];
    const float* Wq = (const float*)d_in[1];
    const float* Wk = (const float*)d_in[2];
    const float* Wv = (const float*)d_in[3];
    const float* bq = (const float*)d_in[4];
    const float* bk = (const float*)d_in[5];
    const float* bv = (const float*)d_in[6];
    float* out = (float*)d_out;

    // Workspace: Q, K, V each [B][N][C] fp32 (16 MB each, 48 MB total)
    float* Q = (float*)d_ws;
    float* K = Q + (size_t)NB * NN * NC;
    float* V = K + (size_t)NB * NN * NC;

    qkv_proj_kernel<<<dim3(NN / 64, NC / 64, NB), 256, 0, stream>>>(
        x, Wq, Wk, Wv, bq, bk, bv, Q, K, V);
    flash_attn_kernel<<<dim3(NN / 32, NB), 256, 0, stream>>>(Q, K, V, out);
}

// Round 2
// 203.748 us; speedup vs baseline: 11.0213x; 11.0213x over previous
//
#include <hip/hip_runtime.h>

// CNN self-attention: B=4, C=256, H=W=64 -> N=4096.
// Round 1: f16 MFMA flash attention (swapped-operand, zero-shuffle P).
//   K1 qkv_proj : fp32 compute (verified), fp16 outputs; V stored transposed [B][C][N].
//   K2 flash    : 256 blocks (32 qblk x 4 B x 2 kvsplit), 4 waves x 32 q-rows.
//                 S^T = K.Q^T and O^T = V^T.P^T via mfma_f32_32x32x16_f16;
//                 S^T D-regs ARE the PV B-frags (no shuffle). K/V chunks in LDS
//                 with channel-permuted + XOR((row&7)<<4) swizzled layout ->
//                 every A-frag is one conflict-free ds_read_b128.
//   K3 combine  : merge the 2 kv-split partials (normalized fp16 + m,l stats).
// Workspace: Qh,Kh,Vt fp16 (24MB) + Opart fp16 (16MB) + stats (256KB) = 40.25MB.

typedef _Float16 f16;
typedef f16 f16x4 __attribute__((ext_vector_type(4)));
typedef f16 f16x8 __attribute__((ext_vector_type(8)));
typedef float f32x16 __attribute__((ext_vector_type(16)));

#define NB 4
#define NC 256
#define NN 4096
#define KVSPLIT 2
#define KRANGE (NN / KVSPLIT)   // 2048 keys per split
#define NCHUNK (KRANGE / 64)    // 32 chunks of 64 keys

// ---------------- Kernel 1: QKV projection (fp32 math, fp16 out) ----------------
__global__ __launch_bounds__(256) void qkv_proj_kernel(
    const float* __restrict__ x,
    const float* __restrict__ Wq, const float* __restrict__ Wk, const float* __restrict__ Wv,
    const float* __restrict__ bq, const float* __restrict__ bk, const float* __restrict__ bv,
    f16* __restrict__ Qh, f16* __restrict__ Kh, f16* __restrict__ Vt)
{
    const int b  = blockIdx.z;
    const int n0 = blockIdx.x * 64;
    const int c0 = blockIdx.y * 64;
    const int t  = threadIdx.x;

    __shared__ float xs[16][68];
    __shared__ float wqs[16][68];
    __shared__ float wks[16][68];
    __shared__ float wvs[16][68];

    const int tn = (t & 15) * 4;
    const int tc = (t >> 4) * 4;

    float aq[4][4] = {}, ak[4][4] = {}, av[4][4] = {};
    const float* xb = x + (size_t)b * NC * NN;

    for (int k0 = 0; k0 < NC; k0 += 16) {
        __syncthreads();
        {
            const int ci = t >> 4;
            const int nb = (t & 15) * 4;
            *(float4*)&xs[ci][nb] =
                *(const float4*)(xb + (size_t)(k0 + ci) * NN + n0 + nb);
        }
        {
            const int c  = t >> 2;
            const int cb = (t & 3) * 4;
            const float4 q4 = *(const float4*)(Wq + (size_t)(c0 + c) * NC + k0 + cb);
            const float4 k4 = *(const float4*)(Wk + (size_t)(c0 + c) * NC + k0 + cb);
            const float4 v4 = *(const float4*)(Wv + (size_t)(c0 + c) * NC + k0 + cb);
            wqs[cb + 0][c] = q4.x; wqs[cb + 1][c] = q4.y; wqs[cb + 2][c] = q4.z; wqs[cb + 3][c] = q4.w;
            wks[cb + 0][c] = k4.x; wks[cb + 1][c] = k4.y; wks[cb + 2][c] = k4.z; wks[cb + 3][c] = k4.w;
            wvs[cb + 0][c] = v4.x; wvs[cb + 1][c] = v4.y; wvs[cb + 2][c] = v4.z; wvs[cb + 3][c] = v4.w;
        }
        __syncthreads();
        #pragma unroll
        for (int kk = 0; kk < 16; ++kk) {
            float a[4], wq_[4], wk_[4], wv_[4];
            *(float4*)a   = *(const float4*)&xs[kk][tn];
            *(float4*)wq_ = *(const float4*)&wqs[kk][tc];
            *(float4*)wk_ = *(const float4*)&wks[kk][tc];
            *(float4*)wv_ = *(const float4*)&wvs[kk][tc];
            #pragma unroll
            for (int i = 0; i < 4; ++i)
                #pragma unroll
                for (int j = 0; j < 4; ++j) {
                    aq[i][j] += a[i] * wq_[j];
                    ak[i][j] += a[i] * wk_[j];
                    av[i][j] += a[i] * wv_[j];
                }
        }
    }

    float bqv[4], bkv[4], bvv[4];
    *(float4*)bqv = *(const float4*)(bq + c0 + tc);
    *(float4*)bkv = *(const float4*)(bk + c0 + tc);
    *(float4*)bvv = *(const float4*)(bv + c0 + tc);

    #pragma unroll
    for (int i = 0; i < 4; ++i) {
        f16x4 q4, k4;
        #pragma unroll
        for (int j = 0; j < 4; ++j) {
            q4[j] = (f16)(aq[i][j] + bqv[j]);
            k4[j] = (f16)(ak[i][j] + bkv[j]);
        }
        const size_t base = ((size_t)b * NN + n0 + tn + i) * NC + c0 + tc;
        *(f16x4*)(Qh + base) = q4;
        *(f16x4*)(Kh + base) = k4;
    }
    #pragma unroll
    for (int j = 0; j < 4; ++j) {
        f16x4 v4;
        #pragma unroll
        for (int i = 0; i < 4; ++i) v4[i] = (f16)(av[i][j] + bvv[j]);
        *(f16x4*)(Vt + ((size_t)b * NC + c0 + tc + j) * NN + n0 + tn) = v4;
    }
}

// ---------------- Kernel 2: MFMA flash attention ----------------
// LDS K layout: row=key (64 x 512B). Within a 16-channel group, channel w sits
// at slot w^12 if bit2^bit3 else w, so A-frag {4g+j, 8+4g+j} is 16B contiguous.
// Byte col is XOR'd with (row&7)<<4 -> conflict-free ds_read_b128.
// LDS V layout: row=channel (256 x 128B), same permutation along keys.
__global__ __launch_bounds__(256, 1) void flash_mfma_kernel(
    const f16* __restrict__ Qh, const f16* __restrict__ Kh, const f16* __restrict__ Vt,
    f16* __restrict__ Op, float* __restrict__ Mst, float* __restrict__ Lst)
{
    const int t     = threadIdx.x;
    const int b     = blockIdx.y;
    const int split = blockIdx.z;
    const int wv    = t >> 6;
    const int l     = t & 63;
    const int ln    = l & 31;
    const int g     = l >> 5;
    const int q0    = blockIdx.x * 128 + wv * 32;
    const int qrow  = q0 + ln;

    __shared__ char ldsK[64 * 512];   // 32 KB
    __shared__ char ldsV[256 * 128];  // 32 KB

    // ---- Q fragments (held in registers for the whole kernel) ----
    f16x8 qf[16];
    {
        const f16* Qb = Qh + ((size_t)b * NN + qrow) * NC;
        #pragma unroll
        for (int cs = 0; cs < 16; ++cs) {
            f16x4 lo = *(const f16x4*)(Qb + cs * 16 + 4 * g);
            f16x4 hi = *(const f16x4*)(Qb + cs * 16 + 8 + 4 * g);
            qf[cs] = __builtin_shufflevector(lo, hi, 0, 1, 2, 3, 4, 5, 6, 7);
        }
    }

    f32x16 o[8];
    #pragma unroll
    for (int ct = 0; ct < 8; ++ct)
        #pragma unroll
        for (int r = 0; r < 16; ++r) o[ct][r] = 0.0f;

    float mrun = -1e30f, lrun = 0.0f;
    const int key_base = split * KRANGE;

    uint4 kreg[8], vreg[8];

#define LOAD_CHUNK(CH) do {                                                          \
        const int key0_ = key_base + (CH) * 64;                                      \
        _Pragma("unroll")                                                            \
        for (int i = 0; i < 8; ++i) {                                                \
            int u = i * 256 + t;                                                     \
            kreg[i] = *(const uint4*)(Kh + ((size_t)b * NN + key0_ + (u >> 5)) * NC  \
                                          + (u & 31) * 8);                           \
        }                                                                            \
        _Pragma("unroll")                                                            \
        for (int i = 0; i < 8; ++i) {                                                \
            int u = i * 256 + t;                                                     \
            vreg[i] = *(const uint4*)(Vt + ((size_t)b * NC + (u >> 3)) * NN          \
                                          + key0_ + (u & 7) * 8);                    \
        }                                                                            \
    } while (0)

#define WRITE_LDS() do {                                                             \
        _Pragma("unroll")                                                            \
        for (int i = 0; i < 8; ++i) {                                                \
            int u = i * 256 + t;                                                     \
            int row = u >> 5, cu = u & 31;                                           \
            int colA = (cu >> 1) * 32 + (cu & 1) * 8;                                \
            int sw = (row & 7) << 4;                                                 \
            *(unsigned long long*)(ldsK + row * 512 + (colA ^ sw)) =                 \
                ((unsigned long long)kreg[i].y << 32) | kreg[i].x;                   \
            *(unsigned long long*)(ldsK + row * 512 + ((colA + 16) ^ sw)) =          \
                ((unsigned long long)kreg[i].w << 32) | kreg[i].z;                   \
        }                                                                            \
        _Pragma("unroll")                                                            \
        for (int i = 0; i < 8; ++i) {                                                \
            int u = i * 256 + t;                                                     \
            int c = u >> 3, ku = u & 7;                                              \
            int colA = (ku >> 1) * 32 + (ku & 1) * 8;                                \
            int sw = (c & 7) << 4;                                                   \
            *(unsigned long long*)(ldsV + c * 128 + (colA ^ sw)) =                   \
                ((unsigned long long)vreg[i].y << 32) | vreg[i].x;                   \
            *(unsigned long long*)(ldsV + c * 128 + ((colA + 16) ^ sw)) =            \
                ((unsigned long long)vreg[i].w << 32) | vreg[i].z;                   \
        }                                                                            \
    } while (0)

    LOAD_CHUNK(0);

    for (int ch = 0; ch < NCHUNK; ++ch) {
        __syncthreads();          // previous chunk's compute done
        WRITE_LDS();
        __syncthreads();
        if (ch + 1 < NCHUNK) LOAD_CHUNK(ch + 1);   // prefetch overlaps compute

        // ---- S^T = K . Q^T : two 32-key tiles ----
        f32x16 s0, s1;
        #pragma unroll
        for (int r = 0; r < 16; ++r) { s0[r] = 0.0f; s1[r] = 0.0f; }
        const int ksw = (ln & 7) << 4;
        #pragma unroll
        for (int cs = 0; cs < 16; ++cs) {
            const int col = (cs * 32 + g * 16) ^ ksw;
            f16x8 a0 = *(const f16x8*)(ldsK + ln * 512 + col);
            f16x8 a1 = *(const f16x8*)(ldsK + (32 + ln) * 512 + col);
            s0 = __builtin_amdgcn_mfma_f32_32x32x16_f16(a0, qf[cs], s0, 0, 0, 0);
            s1 = __builtin_amdgcn_mfma_f32_32x32x16_f16(a1, qf[cs], s1, 0, 0, 0);
        }

        // ---- online softmax (lane holds 32 keys for query q = ln) ----
        float mt = fmaxf(s0[0], s1[0]);
        #pragma unroll
        for (int r = 1; r < 16; ++r) mt = fmaxf(mt, fmaxf(s0[r], s1[r]));
        mt = fmaxf(mt, __shfl_xor(mt, 32));
        const float mnew  = fmaxf(mrun, mt);
        const float alpha = __expf(mrun - mnew);
        mrun = mnew;

        float ps = 0.0f;
        f16 p0[16], p1[16];
        #pragma unroll
        for (int r = 0; r < 16; ++r) {
            float e0 = __expf(s0[r] - mnew);
            float e1 = __expf(s1[r] - mnew);
            ps += e0 + e1;
            p0[r] = (f16)e0;
            p1[r] = (f16)e1;
        }
        ps += __shfl_xor(ps, 32);
        lrun = lrun * alpha + ps;

        #pragma unroll
        for (int ct = 0; ct < 8; ++ct)
            #pragma unroll
            for (int r = 0; r < 16; ++r) o[ct][r] *= alpha;

        // ---- P-frags: S^T D-regs map 1:1 onto PV B-frag layout ----
        f16x8 pf[4];
        #pragma unroll
        for (int j = 0; j < 8; ++j) {
            pf[0][j] = p0[j];
            pf[1][j] = p0[8 + j];
            pf[2][j] = p1[j];
            pf[3][j] = p1[8 + j];
        }

        // ---- O^T += V^T . P^T ----
        const int vsw = (ln & 7) << 4;
        #pragma unroll
        for (int ct = 0; ct < 8; ++ct) {
            const int vrow = (ct * 32 + ln) * 128;
            #pragma unroll
            for (int s = 0; s < 4; ++s) {
                f16x8 va = *(const f16x8*)(ldsV + vrow + ((s * 32 + g * 16) ^ vsw));
                o[ct] = __builtin_amdgcn_mfma_f32_32x32x16_f16(va, pf[s], o[ct], 0, 0, 0);
            }
        }
    }
#undef LOAD_CHUNK
#undef WRITE_LDS

    // ---- epilogue: store normalized partial (fp16) + stats ----
    const float invl = 1.0f / lrun;
    #pragma unroll
    for (int ct = 0; ct < 8; ++ct)
        #pragma unroll
        for (int r = 0; r < 16; ++r) {
            const int c = ct * 32 + (r & 3) + 8 * (r >> 2) + 4 * g;
            Op[((size_t)(split * NB + b) * NC + c) * NN + qrow] = (f16)(o[ct][r] * invl);
        }
    if (g == 0) {
        Mst[(split * NB + b) * NN + qrow] = mrun;
        Lst[(split * NB + b) * NN + qrow] = lrun;
    }
}

// ---------------- Kernel 3: combine kv-split partials ----------------
__global__ __launch_bounds__(256) void combine_kernel(
    const f16* __restrict__ Op, const float* __restrict__ Mst, const float* __restrict__ Lst,
    float* __restrict__ out)
{
    const int t = threadIdx.x;
    const int b = blockIdx.y;
    const int n = blockIdx.x * 64 + (t & 63);

    const int s0i = b * NN + n;
    const int s1i = (NB + b) * NN + n;
    const float m0 = Mst[s0i], m1 = Mst[s1i];
    const float l0 = Lst[s0i], l1 = Lst[s1i];
    const float mm = fmaxf(m0, m1);
    float w0 = __expf(m0 - mm) * l0;
    float w1 = __expf(m1 - mm) * l1;
    const float inv = 1.0f / (w0 + w1);
    w0 *= inv; w1 *= inv;

    for (int c = (t >> 6); c < NC; c += 4) {
        const size_t i0 = ((size_t)b * NC + c) * NN + n;
        const size_t i1 = ((size_t)(NB + b) * NC + c) * NN + n;
        out[i0] = w0 * (float)Op[i0] + w1 * (float)Op[i1];
    }
}

extern "C" void kernel_launch(void* const* d_in, const int* in_sizes, int n_in,
                              void* d_out, int out_size, void* d_ws, size_t ws_size,
                              hipStream_t stream)
{
    const float* x  = (const float*)d_in[0];
    const float* Wq = (const float*)d_in[1];
    const float* Wk = (const float*)d_in[2];
    const float* Wv = (const float*)d_in[3];
    const float* bq = (const float*)d_in[4];
    const float* bk = (const float*)d_in[5];
    const float* bv = (const float*)d_in[6];
    float* out = (float*)d_out;

    // Workspace layout (40.25 MB)
    f16* Qh = (f16*)d_ws;                          // [B][N][C]  8 MB
    f16* Kh = Qh + (size_t)NB * NN * NC;           // [B][N][C]  8 MB
    f16* Vt = Kh + (size_t)NB * NN * NC;           // [B][C][N]  8 MB
    f16* Op = Vt + (size_t)NB * NN * NC;           // [split][B][C][N] fp16, 16 MB
    float* Mst = (float*)(Op + (size_t)KVSPLIT * NB * NC * NN);  // [split][B][N]
    float* Lst = Mst + (size_t)KVSPLIT * NB * NN;

    qkv_proj_kernel<<<dim3(NN / 64, NC / 64, NB), 256, 0, stream>>>(
        x, Wq, Wk, Wv, bq, bk, bv, Qh, Kh, Vt);
    flash_mfma_kernel<<<dim3(NN / 128, NB, KVSPLIT), 256, 0, stream>>>(
        Qh, Kh, Vt, Op, Mst, Lst);
    combine_kernel<<<dim3(NN / 64, NB), 256, 0, stream>>>(Op, Mst, Lst, out);
}

// Round 3
// 167.388 us; speedup vs baseline: 13.4153x; 1.2172x over previous
//
#include <hip/hip_runtime.h>

// CNN self-attention: B=4, C=256, H=W=64 -> N=4096.
// Round 2: occupancy (KVSPLIT=4 -> 2 waves/SIMD), global_load_lds staging
//          (linear LDS dest + pre-swizzled global src), MFMA qkv projection.
// Workspace: Qh,Kh,Vt f16 (24MB) + Op f16 (32MB) + stats (512KB) + Wh (384KB) ~ 57MB.

typedef _Float16 f16;
typedef f16 f16x4 __attribute__((ext_vector_type(4)));
typedef f16 f16x8 __attribute__((ext_vector_type(8)));
typedef float f32x16 __attribute__((ext_vector_type(16)));

#define NB 4
#define NC 256
#define NN 4096
#define KVSPLIT 4
#define KRANGE (NN / KVSPLIT)   // 1024 keys per split
#define NCHUNK (KRANGE / 64)    // 16 chunks of 64 keys

typedef const __attribute__((address_space(1))) void* gas_t;
typedef __attribute__((address_space(3))) void* las_t;

__device__ __forceinline__ void load_lds16(const void* g, void* l) {
    // async global->LDS DMA: LDS dest = uniform base + lane*16 (linear)
    __builtin_amdgcn_global_load_lds((gas_t)g, (las_t)l, 16, 0, 0);
}

// ---------------- Kernel 0: W fp32 -> f16 ----------------
__global__ __launch_bounds__(256) void wcvt_kernel(
    const float* __restrict__ Wq, const float* __restrict__ Wk,
    const float* __restrict__ Wv, f16* __restrict__ Wh)
{
    const int idx = blockIdx.x * 256 + threadIdx.x;   // grid = 768 blocks
    const float* s = (idx < 65536) ? Wq : (idx < 131072 ? Wk : Wv);
    Wh[idx] = (f16)s[idx & 65535];
}

// ---------------- Kernel 1: QKV projection via MFMA ----------------
// Block: (b, 64-col n-tile). x staged transposed [n][ci] f16 in LDS
// (granule-swizzled). Wave wv computes out-channels [wv*64, wv*64+64) for
// Q, K, V sequentially (A = W-frags from global f16, B = x-frags from LDS).
// Epilogue transposes through LDS for coalesced stores.
// Qh,Kh: [B][N][C]. Vt: [B][C][N] with keys permuted {0-3,8-11,4-7,12-15}
// within each 16-group (so flash's V A-frags are 16B-contiguous granules).
__global__ __launch_bounds__(256) void qkv_mfma_kernel(
    const float* __restrict__ x, const f16* __restrict__ Wh,
    const float* __restrict__ bq, const float* __restrict__ bk, const float* __restrict__ bv,
    f16* __restrict__ Qh, f16* __restrict__ Kh, f16* __restrict__ Vt)
{
    const int b  = blockIdx.y;
    const int n0 = blockIdx.x * 64;
    const int t  = threadIdx.x;
    const int wv = t >> 6, l = t & 63, ln = l & 31, g = l >> 5;

    __shared__ char xs[64 * 512];   // x^T tile [n][ci], swizzled granules
    __shared__ char st[32768];      // output staging

    // ---- stage x -> f16 transposed ----
    {
        const int ci0 = t >> 4;
        const int nq  = (t & 15) * 4;
        for (int it = 0; it < 16; ++it) {
            const int ci = it * 16 + ci0;
            float v4[4];
            *(float4*)v4 = *(const float4*)(x + ((size_t)b * NC + ci) * NN + n0 + nq);
            const int gr = ci >> 3, lo = (ci & 7) * 2;
            #pragma unroll
            for (int j = 0; j < 4; ++j) {
                const int n = nq + j;
                *(f16*)(xs + n * 512 + ((gr ^ (n & 7)) * 16 + lo)) = (f16)v4[j];
            }
        }
    }
    __syncthreads();

    const int c0 = wv * 64;
    for (int m = 0; m < 3; ++m) {
        const f16*  W    = Wh + m * (NC * NC);
        const float* bias = (m == 0) ? bq : (m == 1 ? bk : bv);

        f32x16 acc[2][2];
        #pragma unroll
        for (int i = 0; i < 2; ++i)
            #pragma unroll
            for (int j = 0; j < 2; ++j)
                #pragma unroll
                for (int r = 0; r < 16; ++r) acc[i][j][r] = 0.0f;

        #pragma unroll
        for (int cs = 0; cs < 16; ++cs) {
            f16x8 a0 = *(const f16x8*)(W + (size_t)(c0 + ln) * NC + cs * 16 + 8 * g);
            f16x8 a1 = *(const f16x8*)(W + (size_t)(c0 + 32 + ln) * NC + cs * 16 + 8 * g);
            const int xb = (cs * 32 + g * 16) ^ ((ln & 7) << 4);
            f16x8 b0 = *(const f16x8*)(xs + ln * 512 + xb);
            f16x8 b1 = *(const f16x8*)(xs + (32 + ln) * 512 + xb);
            acc[0][0] = __builtin_amdgcn_mfma_f32_32x32x16_f16(a0, b0, acc[0][0], 0, 0, 0);
            acc[0][1] = __builtin_amdgcn_mfma_f32_32x32x16_f16(a0, b1, acc[0][1], 0, 0, 0);
            acc[1][0] = __builtin_amdgcn_mfma_f32_32x32x16_f16(a1, b0, acc[1][0], 0, 0, 0);
            acc[1][1] = __builtin_amdgcn_mfma_f32_32x32x16_f16(a1, b1, acc[1][1], 0, 0, 0);
        }

        __syncthreads();   // staging buffer free (prev output's stores done)
        if (m < 2) {
            // stage [n][c] f16, granule-swizzled; pack 4 c-consecutive regs
            #pragma unroll
            for (int ct = 0; ct < 2; ++ct)
                #pragma unroll
                for (int nt = 0; nt < 2; ++nt)
                    #pragma unroll
                    for (int q = 0; q < 4; ++q) {
                        const int cb = c0 + ct * 32 + 8 * q + 4 * g;
                        f16x4 pk;
                        #pragma unroll
                        for (int j = 0; j < 4; ++j)
                            pk[j] = (f16)(acc[ct][nt][q * 4 + j] + bias[cb + j]);
                        const int n  = nt * 32 + ln;
                        const int g8 = cb >> 3;
                        *(f16x4*)(st + n * 512 + ((g8 ^ (n & 7)) * 16 + (cb & 7) * 2)) = pk;
                    }
            __syncthreads();
            f16* dst = (m == 0) ? Qh : Kh;
            const int gi  = t & 31;
            const int nb8 = (t >> 5) * 8;
            #pragma unroll
            for (int k = 0; k < 8; ++k) {
                const int n = nb8 + k;
                const uint4 d = *(const uint4*)(st + n * 512 + ((gi ^ (n & 7)) << 4));
                *(uint4*)(dst + ((size_t)b * NN + n0 + n) * NC + gi * 8) = d;
            }
        } else {
            // V: stage [c][n] with key-perm + slot-swizzle
            #pragma unroll
            for (int ct = 0; ct < 2; ++ct)
                #pragma unroll
                for (int nt = 0; nt < 2; ++nt) {
                    const int n  = nt * 32 + ln;
                    const int pn = (n & ~15) | (n & 3) | ((n & 8) >> 1) | ((n & 4) << 1);
                    #pragma unroll
                    for (int r = 0; r < 16; ++r) {
                        const int c = c0 + ct * 32 + (r & 3) + 8 * (r >> 2) + 4 * g;
                        *(f16*)(st + c * 128 + ((pn * 2) ^ ((c & 7) << 4))) =
                            (f16)(acc[ct][nt][r] + bias[c]);
                    }
                }
            __syncthreads();
            #pragma unroll
            for (int ci = 0; ci < 8; ++ci) {
                const int c = ci * 32 + (t >> 3);
                const int s = t & 7;
                const uint4 d = *(const uint4*)(st + c * 128 + ((s ^ (c & 7)) << 4));
                *(uint4*)(Vt + ((size_t)b * NC + c) * NN + n0 + s * 8) = d;
            }
        }
    }
}

// ---------------- Kernel 2: MFMA flash attention ----------------
// 512 blocks (32 qtiles x 4 B x 4 kvsplit) = 2 blocks/CU = 2 waves/SIMD.
// K/V chunks staged via global_load_lds (linear dest, pre-swizzled src).
// LDS K: [key row 512B], granule c16 holds global granule c16^(row&7)
//        (plain contiguous channels). LDS V: [ch row 128B], granule s8 holds
//        global granule s8^(c&7) (keys pre-permuted in Vt).
__global__ __launch_bounds__(256, 2) void flash_mfma_kernel(
    const f16* __restrict__ Qh, const f16* __restrict__ Kh, const f16* __restrict__ Vt,
    f16* __restrict__ Op, float* __restrict__ Mst, float* __restrict__ Lst)
{
    const int t     = threadIdx.x;
    const int b     = blockIdx.y;
    const int split = blockIdx.z;
    const int wv    = t >> 6;
    const int l     = t & 63;
    const int ln    = l & 31;
    const int g     = l >> 5;
    const int q0    = blockIdx.x * 128 + wv * 32;
    const int qrow  = q0 + ln;

    __shared__ char ldsK[64 * 512];   // 32 KB
    __shared__ char ldsV[256 * 128];  // 32 KB

    // ---- Q fragments: contiguous 8-channel granules (match K LDS pairing) ----
    f16x8 qf[16];
    {
        const f16* Qb = Qh + ((size_t)b * NN + qrow) * NC;
        #pragma unroll
        for (int cs = 0; cs < 16; ++cs)
            qf[cs] = *(const f16x8*)(Qb + cs * 16 + 8 * g);
    }

    f32x16 o[8];
    #pragma unroll
    for (int ct = 0; ct < 8; ++ct)
        #pragma unroll
        for (int r = 0; r < 16; ++r) o[ct][r] = 0.0f;

    float mrun = -1e30f, lrun = 0.0f;
    const int key_base = split * KRANGE;
    const f16* KhB = Kh + (size_t)b * NN * NC;
    const f16* VtB = Vt + (size_t)b * NC * NN;

    for (int ch = 0; ch < NCHUNK; ++ch) {
        const int key0 = key_base + ch * 64;
        __syncthreads();   // all waves done reading previous chunk
        // ---- K DMA: 8 instrs/wave, each 2 key-rows of 512B ----
        #pragma unroll
        for (int j = 0; j < 8; ++j) {
            const int base = (wv * 8 + j) * 1024;
            const int row  = (wv * 8 + j) * 2 + (l >> 5);
            const int u    = (l & 31) ^ (row & 7);
            load_lds16(KhB + (size_t)(key0 + row) * NC + u * 8, ldsK + base);
        }
        // ---- V DMA: 8 instrs/wave, each 8 channel-rows of 128B ----
        #pragma unroll
        for (int j = 0; j < 8; ++j) {
            const int base = (wv * 8 + j) * 1024;
            const int c    = (wv * 8 + j) * 8 + (l >> 3);
            const int u    = (l & 7) ^ (c & 7);
            load_lds16(VtB + (size_t)c * NN + key0 + u * 8, ldsV + base);
        }
        asm volatile("s_waitcnt vmcnt(0)" ::: "memory");
        __syncthreads();   // all waves' DMA landed

        // ---- S^T = K . Q^T ----
        f32x16 s0, s1;
        #pragma unroll
        for (int r = 0; r < 16; ++r) { s0[r] = 0.0f; s1[r] = 0.0f; }
        const int ksw = (ln & 7) << 4;
        __builtin_amdgcn_s_setprio(1);
        #pragma unroll
        for (int cs = 0; cs < 16; ++cs) {
            const int col = (cs * 32 + g * 16) ^ ksw;
            f16x8 a0 = *(const f16x8*)(ldsK + ln * 512 + col);
            f16x8 a1 = *(const f16x8*)(ldsK + (32 + ln) * 512 + col);
            s0 = __builtin_amdgcn_mfma_f32_32x32x16_f16(a0, qf[cs], s0, 0, 0, 0);
            s1 = __builtin_amdgcn_mfma_f32_32x32x16_f16(a1, qf[cs], s1, 0, 0, 0);
        }
        __builtin_amdgcn_s_setprio(0);

        // ---- online softmax (lane owns 32 keys of query q = ln) ----
        float mt = fmaxf(s0[0], s1[0]);
        #pragma unroll
        for (int r = 1; r < 16; ++r) mt = fmaxf(mt, fmaxf(s0[r], s1[r]));
        mt = fmaxf(mt, __shfl_xor(mt, 32));
        const float mnew  = fmaxf(mrun, mt);
        const float alpha = __expf(mrun - mnew);
        mrun = mnew;

        float ps = 0.0f;
        f16x8 pf[4];   // S^T D-regs map 1:1 onto PV B-frag layout
        #pragma unroll
        for (int r = 0; r < 16; ++r) {
            const float e0 = __expf(s0[r] - mnew);
            const float e1 = __expf(s1[r] - mnew);
            ps += e0 + e1;
            pf[r >> 3][r & 7]     = (f16)e0;
            pf[2 + (r >> 3)][r & 7] = (f16)e1;
        }
        ps += __shfl_xor(ps, 32);
        lrun = lrun * alpha + ps;

        #pragma unroll
        for (int ct = 0; ct < 8; ++ct)
            #pragma unroll
            for (int r = 0; r < 16; ++r) o[ct][r] *= alpha;

        // ---- O^T += V^T . P^T ----
        const int vsw = (ln & 7) << 4;
        __builtin_amdgcn_s_setprio(1);
        #pragma unroll
        for (int ct = 0; ct < 8; ++ct) {
            const int vrow = (ct * 32 + ln) * 128;
            #pragma unroll
            for (int s = 0; s < 4; ++s) {
                f16x8 va = *(const f16x8*)(ldsV + vrow + ((s * 32 + g * 16) ^ vsw));
                o[ct] = __builtin_amdgcn_mfma_f32_32x32x16_f16(va, pf[s], o[ct], 0, 0, 0);
            }
        }
        __builtin_amdgcn_s_setprio(0);
    }

    // ---- epilogue: normalized partial (f16) + stats ----
    const float invl = 1.0f / lrun;
    #pragma unroll
    for (int ct = 0; ct < 8; ++ct)
        #pragma unroll
        for (int r = 0; r < 16; ++r) {
            const int c = ct * 32 + (r & 3) + 8 * (r >> 2) + 4 * g;
            Op[((size_t)(split * NB + b) * NC + c) * NN + qrow] = (f16)(o[ct][r] * invl);
        }
    if (g == 0) {
        Mst[(split * NB + b) * NN + qrow] = mrun;
        Lst[(split * NB + b) * NN + qrow] = lrun;
    }
}

// ---------------- Kernel 3: combine kv-split partials ----------------
__global__ __launch_bounds__(256) void combine_kernel(
    const f16* __restrict__ Op, const float* __restrict__ Mst, const float* __restrict__ Lst,
    float* __restrict__ out)
{
    const int t = threadIdx.x;
    const int b = blockIdx.y;
    const int n = blockIdx.x * 64 + (t & 63);

    float w[KVSPLIT];
    float mm = -1e30f;
    #pragma unroll
    for (int s = 0; s < KVSPLIT; ++s) {
        w[s] = Mst[(s * NB + b) * NN + n];
        mm = fmaxf(mm, w[s]);
    }
    float tot = 0.0f;
    #pragma unroll
    for (int s = 0; s < KVSPLIT; ++s) {
        w[s] = __expf(w[s] - mm) * Lst[(s * NB + b) * NN + n];
        tot += w[s];
    }
    const float inv = 1.0f / tot;
    #pragma unroll
    for (int s = 0; s < KVSPLIT; ++s) w[s] *= inv;

    for (int c = (t >> 6); c < NC; c += 4) {
        float acc = 0.0f;
        #pragma unroll
        for (int s = 0; s < KVSPLIT; ++s)
            acc += w[s] * (float)Op[((size_t)(s * NB + b) * NC + c) * NN + n];
        out[((size_t)b * NC + c) * NN + n] = acc;
    }
}

extern "C" void kernel_launch(void* const* d_in, const int* in_sizes, int n_in,
                              void* d_out, int out_size, void* d_ws, size_t ws_size,
                              hipStream_t stream)
{
    const float* x  = (const float*)d_in[0];
    const float* Wq = (const float*)d_in[1];
    const float* Wk = (const float*)d_in[2];
    const float* Wv = (const float*)d_in[3];
    const float* bq = (const float*)d_in[4];
    const float* bk = (const float*)d_in[5];
    const float* bv = (const float*)d_in[6];
    float* out = (float*)d_out;

    // Workspace layout (~57 MB)
    f16* Qh = (f16*)d_ws;                                       // 8 MB
    f16* Kh = Qh + (size_t)NB * NN * NC;                        // 8 MB
    f16* Vt = Kh + (size_t)NB * NN * NC;                        // 8 MB
    f16* Op = Vt + (size_t)NB * NN * NC;                        // 32 MB
    float* Mst = (float*)(Op + (size_t)KVSPLIT * NB * NC * NN); // 256 KB
    float* Lst = Mst + (size_t)KVSPLIT * NB * NN;               // 256 KB
    f16*  Wh  = (f16*)(Lst + (size_t)KVSPLIT * NB * NN);        // 384 KB

    wcvt_kernel<<<768, 256, 0, stream>>>(Wq, Wk, Wv, Wh);
    qkv_mfma_kernel<<<dim3(NN / 64, NB), 256, 0, stream>>>(
        x, Wh, bq, bk, bv, Qh, Kh, Vt);
    flash_mfma_kernel<<<dim3(NN / 128, NB, KVSPLIT), 256, 0, stream>>>(
        Qh, Kh, Vt, Op, Mst, Lst);
    combine_kernel<<<dim3(NN / 64, NB), 256, 0, stream>>>(Op, Mst, Lst, out);
}

// Round 4
// 131.949 us; speedup vs baseline: 17.0185x; 1.2686x over previous
//
#include <hip/hip_runtime.h>

// CNN self-attention: B=4, C=256, H=W=64 -> N=4096.
// Round 3: double-buffered DMA flash (counted vmcnt(8) + raw s_barrier, no
//          syncthreads drain), 512-thread blocks 1/CU (8 waves, 128KB LDS),
//          defer-rescale softmax (T13), XCD-aware block swizzle (T1).
// Workspace: Qh,Kh,Vt f16 (24MB) + Op f16 (32MB) + stats (512KB) + Wh (384KB).

typedef _Float16 f16;
typedef f16 f16x4 __attribute__((ext_vector_type(4)));
typedef f16 f16x8 __attribute__((ext_vector_type(8)));
typedef float f32x16 __attribute__((ext_vector_type(16)));

#define NB 4
#define NC 256
#define NN 4096
#define KVSPLIT 4
#define KRANGE (NN / KVSPLIT)   // 1024 keys per split
#define NCHUNK (KRANGE / 64)    // 16 chunks of 64 keys

typedef const __attribute__((address_space(1))) void* gas_t;
typedef __attribute__((address_space(3))) void* las_t;

__device__ __forceinline__ void load_lds16(const void* g, void* l) {
    // async global->LDS DMA: LDS dest = uniform base + lane*16 (linear)
    __builtin_amdgcn_global_load_lds((gas_t)g, (las_t)l, 16, 0, 0);
}

// ---------------- Kernel 0: W fp32 -> f16 ----------------
__global__ __launch_bounds__(256) void wcvt_kernel(
    const float* __restrict__ Wq, const float* __restrict__ Wk,
    const float* __restrict__ Wv, f16* __restrict__ Wh)
{
    const int idx = blockIdx.x * 256 + threadIdx.x;   // grid = 768 blocks
    const float* s = (idx < 65536) ? Wq : (idx < 131072 ? Wk : Wv);
    Wh[idx] = (f16)s[idx & 65535];
}

// ---------------- Kernel 1: QKV projection via MFMA ----------------
// (unchanged from round 2 — validated)
__global__ __launch_bounds__(256) void qkv_mfma_kernel(
    const float* __restrict__ x, const f16* __restrict__ Wh,
    const float* __restrict__ bq, const float* __restrict__ bk, const float* __restrict__ bv,
    f16* __restrict__ Qh, f16* __restrict__ Kh, f16* __restrict__ Vt)
{
    const int b  = blockIdx.y;
    const int n0 = blockIdx.x * 64;
    const int t  = threadIdx.x;
    const int wv = t >> 6, l = t & 63, ln = l & 31, g = l >> 5;

    __shared__ char xs[64 * 512];   // x^T tile [n][ci], swizzled granules
    __shared__ char st[32768];      // output staging

    {
        const int ci0 = t >> 4;
        const int nq  = (t & 15) * 4;
        for (int it = 0; it < 16; ++it) {
            const int ci = it * 16 + ci0;
            float v4[4];
            *(float4*)v4 = *(const float4*)(x + ((size_t)b * NC + ci) * NN + n0 + nq);
            const int gr = ci >> 3, lo = (ci & 7) * 2;
            #pragma unroll
            for (int j = 0; j < 4; ++j) {
                const int n = nq + j;
                *(f16*)(xs + n * 512 + ((gr ^ (n & 7)) * 16 + lo)) = (f16)v4[j];
            }
        }
    }
    __syncthreads();

    const int c0 = wv * 64;
    for (int m = 0; m < 3; ++m) {
        const f16*  W    = Wh + m * (NC * NC);
        const float* bias = (m == 0) ? bq : (m == 1 ? bk : bv);

        f32x16 acc[2][2];
        #pragma unroll
        for (int i = 0; i < 2; ++i)
            #pragma unroll
            for (int j = 0; j < 2; ++j)
                #pragma unroll
                for (int r = 0; r < 16; ++r) acc[i][j][r] = 0.0f;

        #pragma unroll
        for (int cs = 0; cs < 16; ++cs) {
            f16x8 a0 = *(const f16x8*)(W + (size_t)(c0 + ln) * NC + cs * 16 + 8 * g);
            f16x8 a1 = *(const f16x8*)(W + (size_t)(c0 + 32 + ln) * NC + cs * 16 + 8 * g);
            const int xb = (cs * 32 + g * 16) ^ ((ln & 7) << 4);
            f16x8 b0 = *(const f16x8*)(xs + ln * 512 + xb);
            f16x8 b1 = *(const f16x8*)(xs + (32 + ln) * 512 + xb);
            acc[0][0] = __builtin_amdgcn_mfma_f32_32x32x16_f16(a0, b0, acc[0][0], 0, 0, 0);
            acc[0][1] = __builtin_amdgcn_mfma_f32_32x32x16_f16(a0, b1, acc[0][1], 0, 0, 0);
            acc[1][0] = __builtin_amdgcn_mfma_f32_32x32x16_f16(a1, b0, acc[1][0], 0, 0, 0);
            acc[1][1] = __builtin_amdgcn_mfma_f32_32x32x16_f16(a1, b1, acc[1][1], 0, 0, 0);
        }

        __syncthreads();
        if (m < 2) {
            #pragma unroll
            for (int ct = 0; ct < 2; ++ct)
                #pragma unroll
                for (int nt = 0; nt < 2; ++nt)
                    #pragma unroll
                    for (int q = 0; q < 4; ++q) {
                        const int cb = c0 + ct * 32 + 8 * q + 4 * g;
                        f16x4 pk;
                        #pragma unroll
                        for (int j = 0; j < 4; ++j)
                            pk[j] = (f16)(acc[ct][nt][q * 4 + j] + bias[cb + j]);
                        const int n  = nt * 32 + ln;
                        const int g8 = cb >> 3;
                        *(f16x4*)(st + n * 512 + ((g8 ^ (n & 7)) * 16 + (cb & 7) * 2)) = pk;
                    }
            __syncthreads();
            f16* dst = (m == 0) ? Qh : Kh;
            const int gi  = t & 31;
            const int nb8 = (t >> 5) * 8;
            #pragma unroll
            for (int k = 0; k < 8; ++k) {
                const int n = nb8 + k;
                const uint4 d = *(const uint4*)(st + n * 512 + ((gi ^ (n & 7)) << 4));
                *(uint4*)(dst + ((size_t)b * NN + n0 + n) * NC + gi * 8) = d;
            }
        } else {
            #pragma unroll
            for (int ct = 0; ct < 2; ++ct)
                #pragma unroll
                for (int nt = 0; nt < 2; ++nt) {
                    const int n  = nt * 32 + ln;
                    const int pn = (n & ~15) | (n & 3) | ((n & 8) >> 1) | ((n & 4) << 1);
                    #pragma unroll
                    for (int r = 0; r < 16; ++r) {
                        const int c = c0 + ct * 32 + (r & 3) + 8 * (r >> 2) + 4 * g;
                        *(f16*)(st + c * 128 + ((pn * 2) ^ ((c & 7) << 4))) =
                            (f16)(acc[ct][nt][r] + bias[c]);
                    }
                }
            __syncthreads();
            #pragma unroll
            for (int ci = 0; ci < 8; ++ci) {
                const int c = ci * 32 + (t >> 3);
                const int s = t & 7;
                const uint4 d = *(const uint4*)(st + c * 128 + ((s ^ (c & 7)) << 4));
                *(uint4*)(Vt + ((size_t)b * NC + c) * NN + n0 + s * 8) = d;
            }
        }
    }
}

// ---------------- Kernel 2: MFMA flash attention (double-buffered) ----------------
// 256 blocks x 512 threads = 1 block/CU, 8 waves (2/SIMD), 128KB LDS.
// Per chunk: issue next chunk's DMA -> s_waitcnt vmcnt(8) -> s_barrier ->
// compute -> s_barrier. HBM latency hides under compute; no vmcnt(0) drain.
__global__ __launch_bounds__(512, 2) void flash_mfma_kernel(
    const f16* __restrict__ Qh, const f16* __restrict__ Kh, const f16* __restrict__ Vt,
    f16* __restrict__ Op, float* __restrict__ Mst, float* __restrict__ Lst)
{
    const int t  = threadIdx.x;
    const int wv = t >> 6;
    const int l  = t & 63;
    const int ln = l & 31;
    const int g  = l >> 5;

    // XCD-aware swizzle: the 16 q-tile blocks sharing one (b,split) KV stream
    // land on the same XCD (flat%8 round-robin assumed; perf-only heuristic).
    const int flat  = blockIdx.x;       // 0..255
    const int xcd   = flat & 7;
    const int slot  = flat >> 3;        // 0..31
    const int bs    = xcd * 2 + (slot & 1);   // 0..15
    const int qt    = slot >> 1;        // 0..15
    const int b     = bs >> 2;
    const int split = bs & 3;
    const int qrow  = qt * 256 + wv * 32 + ln;

    __shared__ char ldsK[2 * 32768];   // [buf][64 key-rows x 512B]
    __shared__ char ldsV[2 * 32768];   // [buf][256 ch-rows x 128B]

    // ---- Q fragments (register-resident) ----
    f16x8 qf[16];
    {
        const f16* Qb = Qh + ((size_t)b * NN + qrow) * NC;
        #pragma unroll
        for (int cs = 0; cs < 16; ++cs)
            qf[cs] = *(const f16x8*)(Qb + cs * 16 + 8 * g);
    }

    f32x16 o[8];
    #pragma unroll
    for (int ct = 0; ct < 8; ++ct)
        #pragma unroll
        for (int r = 0; r < 16; ++r) o[ct][r] = 0.0f;

    float mrun = -1e30f, lrun = 0.0f;
    const int key_base = split * KRANGE;
    const f16* KhB = Kh + (size_t)b * NN * NC;
    const f16* VtB = Vt + (size_t)b * NC * NN;

    // 8 DMA instrs / wave / chunk: 4 x (2 key-rows of 512B), 4 x (8 ch-rows of 128B)
#define DMA(CH, BUF) do {                                                            \
        const int key0_ = key_base + (CH) * 64;                                      \
        _Pragma("unroll")                                                            \
        for (int j = 0; j < 4; ++j) {                                                \
            const int r2  = wv * 4 + j;                                              \
            const int row = r2 * 2 + (l >> 5);                                       \
            const int u   = (l & 31) ^ (row & 7);                                    \
            load_lds16(KhB + (size_t)(key0_ + row) * NC + u * 8,                     \
                       ldsK + (BUF) * 32768 + r2 * 1024);                            \
        }                                                                            \
        _Pragma("unroll")                                                            \
        for (int j = 0; j < 4; ++j) {                                                \
            const int c8 = wv * 4 + j;                                               \
            const int c  = c8 * 8 + (l >> 3);                                        \
            const int u  = (l & 7) ^ (c & 7);                                        \
            load_lds16(VtB + (size_t)c * NN + key0_ + u * 8,                         \
                       ldsV + (BUF) * 32768 + c8 * 1024);                            \
        }                                                                            \
    } while (0)

    DMA(0, 0);

    for (int ch = 0; ch < NCHUNK; ++ch) {
        const int cb = ch & 1;
        if (ch + 1 < NCHUNK) {
            DMA(ch + 1, cb ^ 1);
            asm volatile("s_waitcnt vmcnt(8)" ::: "memory");   // this chunk landed
        } else {
            asm volatile("s_waitcnt vmcnt(0)" ::: "memory");
        }
        __builtin_amdgcn_s_barrier();   // all waves' DMA landed (no vmcnt-0 drain)

        const char* K0 = ldsK + cb * 32768;
        const char* V0 = ldsV + cb * 32768;

        // ---- S^T = K . Q^T ----
        f32x16 s0, s1;
        #pragma unroll
        for (int r = 0; r < 16; ++r) { s0[r] = 0.0f; s1[r] = 0.0f; }
        const int ksw = (ln & 7) << 4;
        __builtin_amdgcn_s_setprio(1);
        #pragma unroll
        for (int cs = 0; cs < 16; ++cs) {
            const int col = (cs * 32 + g * 16) ^ ksw;
            f16x8 a0 = *(const f16x8*)(K0 + ln * 512 + col);
            f16x8 a1 = *(const f16x8*)(K0 + (32 + ln) * 512 + col);
            s0 = __builtin_amdgcn_mfma_f32_32x32x16_f16(a0, qf[cs], s0, 0, 0, 0);
            s1 = __builtin_amdgcn_mfma_f32_32x32x16_f16(a1, qf[cs], s1, 0, 0, 0);
        }
        __builtin_amdgcn_s_setprio(0);

        // ---- online softmax with defer-rescale (T13, THR=8) ----
        float mt = fmaxf(s0[0], s1[0]);
        #pragma unroll
        for (int r = 1; r < 16; ++r) mt = fmaxf(mt, fmaxf(s0[r], s1[r]));
        mt = fmaxf(mt, __shfl_xor(mt, 32));
        if (!__all(mt <= mrun + 8.0f)) {
            const float mnew  = fmaxf(mrun, mt);
            const float alpha = __expf(mrun - mnew);
            #pragma unroll
            for (int ct = 0; ct < 8; ++ct)
                #pragma unroll
                for (int r = 0; r < 16; ++r) o[ct][r] *= alpha;
            lrun *= alpha;
            mrun  = mnew;
        }

        float ps = 0.0f;
        f16x8 pf[4];   // S^T D-regs map 1:1 onto PV B-frag layout
        #pragma unroll
        for (int r = 0; r < 16; ++r) {
            const float e0 = __expf(s0[r] - mrun);
            const float e1 = __expf(s1[r] - mrun);
            ps += e0 + e1;
            pf[r >> 3][r & 7]       = (f16)e0;
            pf[2 + (r >> 3)][r & 7] = (f16)e1;
        }
        ps += __shfl_xor(ps, 32);
        lrun += ps;

        // ---- O^T += V^T . P^T ----
        const int vsw = (ln & 7) << 4;
        __builtin_amdgcn_s_setprio(1);
        #pragma unroll
        for (int ct = 0; ct < 8; ++ct) {
            const int vrow = (ct * 32 + ln) * 128;
            #pragma unroll
            for (int s = 0; s < 4; ++s) {
                f16x8 va = *(const f16x8*)(V0 + vrow + ((s * 32 + g * 16) ^ vsw));
                o[ct] = __builtin_amdgcn_mfma_f32_32x32x16_f16(va, pf[s], o[ct], 0, 0, 0);
            }
        }
        __builtin_amdgcn_s_setprio(0);

        __builtin_amdgcn_s_barrier();   // reads done -> next iter may overwrite buf
    }
#undef DMA

    // ---- epilogue: normalized partial (f16) + stats ----
    const float invl = 1.0f / lrun;
    #pragma unroll
    for (int ct = 0; ct < 8; ++ct)
        #pragma unroll
        for (int r = 0; r < 16; ++r) {
            const int c = ct * 32 + (r & 3) + 8 * (r >> 2) + 4 * g;
            Op[((size_t)(split * NB + b) * NC + c) * NN + qrow] = (f16)(o[ct][r] * invl);
        }
    if (g == 0) {
        Mst[(split * NB + b) * NN + qrow] = mrun;
        Lst[(split * NB + b) * NN + qrow] = lrun;
    }
}

// ---------------- Kernel 3: combine kv-split partials ----------------
__global__ __launch_bounds__(256) void combine_kernel(
    const f16* __restrict__ Op, const float* __restrict__ Mst, const float* __restrict__ Lst,
    float* __restrict__ out)
{
    const int t = threadIdx.x;
    const int b = blockIdx.y;
    const int n = blockIdx.x * 64 + (t & 63);

    float w[KVSPLIT];
    float mm = -1e30f;
    #pragma unroll
    for (int s = 0; s < KVSPLIT; ++s) {
        w[s] = Mst[(s * NB + b) * NN + n];
        mm = fmaxf(mm, w[s]);
    }
    float tot = 0.0f;
    #pragma unroll
    for (int s = 0; s < KVSPLIT; ++s) {
        w[s] = __expf(w[s] - mm) * Lst[(s * NB + b) * NN + n];
        tot += w[s];
    }
    const float inv = 1.0f / tot;
    #pragma unroll
    for (int s = 0; s < KVSPLIT; ++s) w[s] *= inv;

    for (int c = (t >> 6); c < NC; c += 4) {
        float acc = 0.0f;
        #pragma unroll
        for (int s = 0; s < KVSPLIT; ++s)
            acc += w[s] * (float)Op[((size_t)(s * NB + b) * NC + c) * NN + n];
        out[((size_t)b * NC + c) * NN + n] = acc;
    }
}

extern "C" void kernel_launch(void* const* d_in, const int* in_sizes, int n_in,
                              void* d_out, int out_size, void* d_ws, size_t ws_size,
                              hipStream_t stream)
{
    const float* x  = (const float*)d_in[0];
    const float* Wq = (const float*)d_in[1];
    const float* Wk = (const float*)d_in[2];
    const float* Wv = (const float*)d_in[3];
    const float* bq = (const float*)d_in[4];
    const float* bk = (const float*)d_in[5];
    const float* bv = (const float*)d_in[6];
    float* out = (float*)d_out;

    // Workspace layout (~57 MB)
    f16* Qh = (f16*)d_ws;                                       // 8 MB
    f16* Kh = Qh + (size_t)NB * NN * NC;                        // 8 MB
    f16* Vt = Kh + (size_t)NB * NN * NC;                        // 8 MB
    f16* Op = Vt + (size_t)NB * NN * NC;                        // 32 MB
    float* Mst = (float*)(Op + (size_t)KVSPLIT * NB * NC * NN); // 256 KB
    float* Lst = Mst + (size_t)KVSPLIT * NB * NN;               // 256 KB
    f16*  Wh  = (f16*)(Lst + (size_t)KVSPLIT * NB * NN);        // 384 KB

    wcvt_kernel<<<768, 256, 0, stream>>>(Wq, Wk, Wv, Wh);
    qkv_mfma_kernel<<<dim3(NN / 64, NB), 256, 0, stream>>>(
        x, Wh, bq, bk, bv, Qh, Kh, Vt);
    flash_mfma_kernel<<<256, 512, 0, stream>>>(Qh, Kh, Vt, Op, Mst, Lst);
    combine_kernel<<<dim3(NN / 64, NB), 256, 0, stream>>>(Op, Mst, Lst, out);
}